// Round 9
// baseline (318.986 us; speedup 1.0000x reference)
//
#include <hip/hip_runtime.h>

#define F 128
#define HP 136      // bf16 LDS row stride (272 B)
#define NB 256      // graph_build blocks (1 per CU, co-resident)
#define SCHUNK 256  // counts per scan chunk

typedef short bf16x8 __attribute__((ext_vector_type(8)));   // 8 bf16 = 4 VGPRs
typedef float f32x4  __attribute__((ext_vector_type(4)));

__device__ __forceinline__ unsigned short f2bf(float f) {
    unsigned int u = __float_as_uint(f);
    u += 0x7fffu + ((u >> 16) & 1u);        // round-to-nearest-even
    return (unsigned short)(u >> 16);
}
__device__ __forceinline__ float bf2f(unsigned short s) {
    return __uint_as_float(((unsigned int)s) << 16);
}

// inter-block barrier: release-fence, arrive, poll, acquire-fence.
// All NB blocks are co-resident (NB=256 = #CUs), so no deadlock.
__device__ __forceinline__ void gridbar(int* flag, int target) {
    __syncthreads();                      // drains each thread's stores (vmcnt) pre-barrier
    if (threadIdx.x == 0) {
        __threadfence();                  // release: writeback this XCD's L2
        atomicAdd(flag, 1);               // device-scope
        while (__hip_atomic_load(flag, __ATOMIC_RELAXED, __HIP_MEMORY_SCOPE_AGENT) < target)
            __builtin_amdgcn_s_sleep(1);
    }
    __syncthreads();
    __threadfence();                      // acquire: invalidate stale cached lines
}

// ---------------- single-pass graph build ----------------
// Z: zero counts + x->bf16 + W pack | H: hist | S1: chunk scan | S2: bsums scan + add | F: fill
__global__ __launch_bounds__(256) void graph_build_kernel(
        const float* __restrict__ x, const float* __restrict__ Ws,
        const float* __restrict__ Wn,
        const int* __restrict__ src, const int* __restrict__ dst,
        unsigned short* __restrict__ xh, unsigned short* __restrict__ Bpack,
        int* __restrict__ counts, int* __restrict__ offsets,
        int* __restrict__ cursor, int* __restrict__ esrc,
        int* __restrict__ bsums, int* __restrict__ flags, int n, int E) {
    int tid = threadIdx.x;
    int bid = blockIdx.x;
    int gid = bid * 256 + tid;
    const int gstride = NB * 256;

    // ---- phase Z ----
    for (int i = gid; i < n; i += gstride) counts[i] = 0;

    for (int idx = gid; idx < 32768; idx += gstride) {   // B-fragment pack of [Ws;Wn]
        int j    = idx & 7;
        int lane = (idx >> 3) & 63;
        int tile = idx >> 9;
        int s = tile >> 3;
        int t = tile & 7;
        int k = s * 32 + (lane >> 4) * 8 + j;
        int c = t * 16 + (lane & 15);
        float v = (k < F) ? Ws[k * F + c] : Wn[(k - F) * F + c];
        Bpack[idx] = f2bf(v);
    }

    for (int idx = gid; idx < n * 16; idx += gstride) {  // convert 8 floats -> bf16x8
        int node = idx >> 4;
        int c = (idx & 15) * 8;
        const float4* p = (const float4*)(x + (size_t)node * F + c);
        float4 v0 = p[0], v1 = p[1];
        bf16x8 o;
        o[0] = (short)f2bf(v0.x); o[1] = (short)f2bf(v0.y);
        o[2] = (short)f2bf(v0.z); o[3] = (short)f2bf(v0.w);
        o[4] = (short)f2bf(v1.x); o[5] = (short)f2bf(v1.y);
        o[6] = (short)f2bf(v1.z); o[7] = (short)f2bf(v1.w);
        *(bf16x8*)(xh + (size_t)node * F + c) = o;
    }
    gridbar(&flags[0], NB);

    // ---- phase H: histogram (no-return atomics pipeline) ----
    for (int e = gid; e < E; e += gstride) atomicAdd(&counts[dst[e]], 1);
    gridbar(&flags[1], NB);

    // ---- phase S1: per-chunk exclusive scan (SCHUNK elems, 1/thread) ----
    __shared__ int wsum[4];
    __shared__ int sexcl[NB];
    __shared__ int total_s;
    int nchunks = (n + SCHUNK - 1) / SCHUNK;     // 196
    int i = bid * SCHUNK + tid;
    int lane = tid & 63, wid = tid >> 6;
    {
        int c = (bid < nchunks && i < n) ? counts[i] : 0;
        int v = c;
        #pragma unroll
        for (int off = 1; off < 64; off <<= 1) {
            int t = __shfl_up(v, off);
            if (lane >= off) v += t;
        }
        if (lane == 63) wsum[wid] = v;
        __syncthreads();
        int wex = 0;
        #pragma unroll
        for (int w = 0; w < 3; ++w) if (w < wid) wex += wsum[w];
        if (bid < nchunks && i < n) offsets[i] = wex + v - c;
        if (bid < nchunks && tid == 255) bsums[bid] = wex + v;
    }
    gridbar(&flags[2], NB);

    // ---- phase S2: scan bsums (replicated per block) + add + cursor ----
    {
        int s2 = (tid < nchunks) ? bsums[tid] : 0;
        int v = s2;
        #pragma unroll
        for (int off = 1; off < 64; off <<= 1) {
            int t = __shfl_up(v, off);
            if (lane >= off) v += t;
        }
        if (lane == 63) wsum[wid] = v;
        __syncthreads();
        int wex = 0;
        #pragma unroll
        for (int w = 0; w < 3; ++w) if (w < wid) wex += wsum[w];
        sexcl[tid] = wex + v - s2;
        if (tid == 255) total_s = wex + v;
        __syncthreads();
        int boff = sexcl[bid];
        if (bid < nchunks && i < n) {
            int vv = offsets[i] + boff;
            offsets[i] = vv;
            cursor[i] = vv;
        }
        if (bid == 0 && tid == 0) offsets[n] = total_s;   // == E
    }
    gridbar(&flags[3], NB);

    // ---- phase F: fill CSR buckets ----
    for (int e = gid; e < E; e += gstride) {
        int p = atomicAdd(&cursor[dst[e]], 1);
        esrc[p] = src[e];
    }
}

// ---------------- fused aggregate + MFMA GEMM, 16 nodes/block (unchanged from R8) ----------------
__global__ __launch_bounds__(256) void agg_gemm_kernel(
        const unsigned short* __restrict__ xh,      // n x 128 bf16
        const int* __restrict__ esrc,
        const int* __restrict__ offsets,
        const unsigned short* __restrict__ Bpack,
        const float* __restrict__ bias,
        float* __restrict__ out, int n) {
    __shared__ __align__(16) unsigned short hs[16 * HP];

    int tid = threadIdx.x;
    int r0 = blockIdx.x * 16;

    // ---- phase A: gather mean ----
    int l16 = tid & 15;
    int g = tid >> 4;              // node 0..15 in tile
    int v = r0 + g;
    float acc[8] = {0.f, 0.f, 0.f, 0.f, 0.f, 0.f, 0.f, 0.f};
    if (v < n) {
        int beg = offsets[v];
        int end = offsets[v + 1];
        for (int j = beg; j < end; ++j) {
            int s = esrc[j];
            bf16x8 xv = *(const bf16x8*)(xh + (size_t)s * F + l16 * 8);
            #pragma unroll
            for (int i = 0; i < 8; ++i) acc[i] += bf2f((unsigned short)xv[i]);
        }
        float r = (end > beg) ? 1.0f / (float)(end - beg) : 0.f;
        #pragma unroll
        for (int i = 0; i < 8; ++i) acc[i] *= r;
    }
    bf16x8 o;
    #pragma unroll
    for (int i = 0; i < 8; ++i) o[i] = (short)f2bf(acc[i]);
    *(bf16x8*)(&hs[g * HP + l16 * 8]) = o;
    __syncthreads();

    // ---- phase B: 4 waves x (16 rows x 32 cols) ----
    int wave = tid >> 6;
    int lane = tid & 63;
    int q = lane >> 4;
    int m = lane & 15;

    f32x4 acc2[2];
    acc2[0] = 0.f; acc2[1] = 0.f;

    int rA = min(r0 + m, n - 1);
    const unsigned short* ap = xh + (size_t)rA * F + q * 8;
    const unsigned short* hp = &hs[m * HP + q * 8];

    #pragma unroll
    for (int s = 0; s < 8; ++s) {
        bf16x8 a = (s < 4) ? *(const bf16x8*)(ap + s * 32)
                           : *(const bf16x8*)(hp + (s - 4) * 32);
        #pragma unroll
        for (int t = 0; t < 2; ++t) {
            bf16x8 bf = *(const bf16x8*)(Bpack + ((size_t)((s * 8 + wave * 2 + t) * 64 + lane)) * 8);
            acc2[t] = __builtin_amdgcn_mfma_f32_16x16x32_bf16(a, bf, acc2[t], 0, 0, 0);
        }
    }

    #pragma unroll
    for (int t = 0; t < 2; ++t) {
        int col = (wave * 2 + t) * 16 + m;
        float bv = bias[col];
        #pragma unroll
        for (int g2 = 0; g2 < 4; ++g2) {
            int row = r0 + q * 4 + g2;
            if (row < n)
                out[(size_t)row * F + col] = fmaxf(acc2[t][g2] + bv, 0.f);
        }
    }
}

extern "C" void kernel_launch(void* const* d_in, const int* in_sizes, int n_in,
                              void* d_out, int out_size, void* d_ws, size_t ws_size,
                              hipStream_t stream) {
    const float* x  = (const float*)d_in[0];
    const float* Ws = (const float*)d_in[1];
    const float* Wn = (const float*)d_in[2];
    const float* b  = (const float*)d_in[3];
    const int* src  = (const int*)d_in[4];
    const int* dst  = (const int*)d_in[5];
    int n = in_sizes[0] / F;      // 50000
    int E = in_sizes[4];          // 600000

    // workspace layout (4B elems):
    //   xh      : n*128 bf16 (x only)     12.8 MB
    //   counts  : n ints
    //   offsets : n+1 ints
    //   cursor  : n ints
    //   esrc    : E ints
    //   bsums   : NB ints
    //   flags   : 16 ints (4 used)
    //   Bpack   : 32768 bf16 (64 KB)
    unsigned short* xh = (unsigned short*)d_ws;
    int* counts  = (int*)(xh + (size_t)n * F);
    int* offsets = counts + n;
    int* cursor  = offsets + (n + 1);
    int* esrc    = cursor + n;
    int* bsums   = esrc + E;
    int* flags   = bsums + NB;
    unsigned short* Bpack = (unsigned short*)(flags + 16);

    float* out = (float*)d_out;

    hipMemsetAsync(flags, 0, 16 * sizeof(int), stream);
    graph_build_kernel<<<NB, 256, 0, stream>>>(x, Ws, Wn, src, dst, xh, Bpack,
                                               counts, offsets, cursor, esrc,
                                               bsums, flags, n, E);
    agg_gemm_kernel<<<(n + 15) / 16, 256, 0, stream>>>(xh, esrc, offsets, Bpack, b, out, n);
}